// Round 3
// baseline (606.494 us; speedup 1.0000x reference)
//
#include <hip/hip_runtime.h>
#include <hip/hip_bf16.h>

#define B_ 64
#define N_ 2048
#define I_ 16
#define J_ 32
#define O_ 32
#define JO_ 1024

typedef __attribute__((ext_vector_type(8))) short bf16x8;
typedef __attribute__((ext_vector_type(4))) float f32x4;
typedef unsigned short u16;
typedef unsigned int u32;

__device__ __forceinline__ float bf2f(u16 u) {
  union { u32 i; float f; } c; c.i = ((u32)u) << 16; return c.f;
}
__device__ __forceinline__ u16 f2bf(float f) {
  union { float f; u32 i; } c; c.f = f;
  u32 r = (c.i + 0x7fffu + ((c.i >> 16) & 1u)) >> 16;
  return (u16)r;
}
__device__ __forceinline__ u32 pack2(float a, float b) {
  return (u32)f2bf(a) | ((u32)f2bf(b) << 16);
}

// ---------------------------------------------------------------------------
// S kernel: s[b][j][o] += sum_{n in chunk, i} (c[b,n,j]*x[b,n,i]) * w[n,j,o,i]
// f32 inputs, converted to bf16 during LDS staging. grid (64 ksplit, 32 j),
// block 256, fp32 atomic accumulate into 256KB s_sum.
// ---------------------------------------------------------------------------
#define S_NPB 32
#define S_CHUNK 8
#define XSTR 136   // 128 + 8 pad, 272B rows (16B aligned)

__global__ __launch_bounds__(256, 2) void s_kernel(
    const float* __restrict__ x, const float* __restrict__ w,
    const u16* __restrict__ cb, float* __restrict__ s_sum, int uniform)
{
  __shared__ u16 xs[B_ * XSTR];   // 17 KB
  __shared__ u16 wb[O_ * XSTR];   // 8.5 KB
  const int tid = threadIdx.x;
  const int lane = tid & 63, wave = tid >> 6;
  const int l15 = lane & 15, quad = lane >> 4;
  const int j = blockIdx.y;
  const int n0 = blockIdx.x * S_NPB;
  f32x4 acc0 = {0.f, 0.f, 0.f, 0.f}, acc1 = {0.f, 0.f, 0.f, 0.f};

  for (int ch = 0; ch < S_NPB / S_CHUNK; ++ch) {
    const int nc = n0 + ch * S_CHUNK;
    __syncthreads();
    // stage c-scaled x: 512 rows (b, ln) of 16 f32 -> bf16
    for (int r = tid; r < B_ * S_CHUNK; r += 256) {
      const int b = r >> 3, ln = r & 7, n = nc + ln;
      const float cv = uniform ? 0.03125f
                               : bf2f(cb[((size_t)b * N_ + n) * J_ + j]);
      const float4* sp = (const float4*)(x + ((size_t)b * N_ + n) * I_);
      float4 f0 = sp[0], f1 = sp[1], f2 = sp[2], f3 = sp[3];
      uint4 d0, d1;
      d0.x = pack2(f0.x * cv, f0.y * cv); d0.y = pack2(f0.z * cv, f0.w * cv);
      d0.z = pack2(f1.x * cv, f1.y * cv); d0.w = pack2(f1.z * cv, f1.w * cv);
      d1.x = pack2(f2.x * cv, f2.y * cv); d1.y = pack2(f2.z * cv, f2.w * cv);
      d1.z = pack2(f3.x * cv, f3.y * cv); d1.w = pack2(f3.z * cv, f3.w * cv);
      uint4* dp = (uint4*)(xs + b * XSTR + ln * I_);
      dp[0] = d0; dp[1] = d1;
    }
    // stage w: 256 rows (ln, o) of 16 f32 -> bf16 — one per thread
    {
      const int ln = tid >> 5, o = tid & 31, n = nc + ln;
      const float4* sp = (const float4*)(w + (((size_t)n * J_ + j) * O_ + o) * I_);
      float4 f0 = sp[0], f1 = sp[1], f2 = sp[2], f3 = sp[3];
      uint4 d0, d1;
      d0.x = pack2(f0.x, f0.y); d0.y = pack2(f0.z, f0.w);
      d0.z = pack2(f1.x, f1.y); d0.w = pack2(f1.z, f1.w);
      d1.x = pack2(f2.x, f2.y); d1.y = pack2(f2.z, f2.w);
      d1.z = pack2(f3.x, f3.y); d1.w = pack2(f3.z, f3.w);
      uint4* dp = (uint4*)(wb + o * XSTR + ln * I_);
      dp[0] = d0; dp[1] = d1;
    }
    __syncthreads();
    #pragma unroll
    for (int ks = 0; ks < 4; ++ks) {
      const int kk = ks * 32 + quad * 8;
      bf16x8 av = *(const bf16x8*)(xs + (wave * 16 + l15) * XSTR + kk);
      bf16x8 b0 = *(const bf16x8*)(wb + l15 * XSTR + kk);
      bf16x8 b1 = *(const bf16x8*)(wb + (16 + l15) * XSTR + kk);
      acc0 = __builtin_amdgcn_mfma_f32_16x16x32_bf16(av, b0, acc0, 0, 0, 0);
      acc1 = __builtin_amdgcn_mfma_f32_16x16x32_bf16(av, b1, acc1, 0, 0, 0);
    }
  }
  // C layout: col = lane&15, row = quad*4 + reg
  #pragma unroll
  for (int r = 0; r < 4; ++r) {
    const int b = wave * 16 + quad * 4 + r;
    atomicAdd(&s_sum[(size_t)b * JO_ + (size_t)j * O_ + l15], acc0[r]);
    atomicAdd(&s_sum[(size_t)b * JO_ + (size_t)j * O_ + 16 + l15], acc1[r]);
  }
}

// ---------------------------------------------------------------------------
// R kernel: squash over o, write v fp32 (and fp32 out on final)
// grid 1024, block 64 (two (b,j) pairs per block)
// ---------------------------------------------------------------------------
__global__ __launch_bounds__(64) void r_kernel(
    const float* __restrict__ s_sum, float* __restrict__ v,
    float* __restrict__ out, int final_)
{
  const int o = threadIdx.x & 31;
  const int pair = blockIdx.x * 2 + (threadIdx.x >> 5);   // pair = b*32 + j
  const size_t off = (size_t)pair * O_ + o;
  float s = s_sum[off];
  float sq = s * s;
  #pragma unroll
  for (int m = 16; m >= 1; m >>= 1) sq += __shfl_xor(sq, m, 64);
  const float scale = sq / (1.f + sq) * rsqrtf(sq + 1e-8f);
  const float vv = scale * s;
  v[off] = vv;
  if (final_) out[off] = vv;
}

// ---------------------------------------------------------------------------
// A kernel: pred = x*w via MFMA (K=16 zero-padded), ag0 = sum_o pred*v0,
// (iter 2: + ag1 with v1), softmax over j -> c (bf16 internal).
// grid (256 n-groups of 8, 4 b-quarters), block 256. f32 inputs.
// ---------------------------------------------------------------------------
#define A_GN 8
#define WSTR 16
#define XSTRA 24

__global__ __launch_bounds__(256, 2) void a_kernel(
    const float* __restrict__ x, const float* __restrict__ w,
    const float* __restrict__ v0, const float* __restrict__ v1,
    u16* __restrict__ cb, int iter)
{
  __shared__ u16 wl[JO_ * WSTR];    // 32 KB
  __shared__ u16 xl[16 * XSTRA];    // 768 B
  __shared__ float ag[16][33];      // 2.1 KB
  const int tid = threadIdx.x;
  const int lane = tid & 63, wave = tid >> 6;
  const int l15 = lane & 15, quad = lane >> 4;
  const int b0 = blockIdx.y * 16;
  const int ng0 = blockIdx.x * A_GN;

  for (int nl = 0; nl < A_GN; ++nl) {
    const int n = ng0 + nl;
    __syncthreads();
    for (int r = tid; r < JO_; r += 256) {
      const float4* sp = (const float4*)(w + ((size_t)n * JO_ + r) * I_);
      float4 f0 = sp[0], f1 = sp[1], f2 = sp[2], f3 = sp[3];
      uint4 d0, d1;
      d0.x = pack2(f0.x, f0.y); d0.y = pack2(f0.z, f0.w);
      d0.z = pack2(f1.x, f1.y); d0.w = pack2(f1.z, f1.w);
      d1.x = pack2(f2.x, f2.y); d1.y = pack2(f2.z, f2.w);
      d1.z = pack2(f3.x, f3.y); d1.w = pack2(f3.z, f3.w);
      uint4* dp = (uint4*)(wl + r * WSTR);
      dp[0] = d0; dp[1] = d1;
    }
    if (tid < 16) {
      const float4* sp = (const float4*)(x + ((size_t)(b0 + tid) * N_ + n) * I_);
      float4 f0 = sp[0], f1 = sp[1], f2 = sp[2], f3 = sp[3];
      uint4 d0, d1;
      d0.x = pack2(f0.x, f0.y); d0.y = pack2(f0.z, f0.w);
      d0.z = pack2(f1.x, f1.y); d0.w = pack2(f1.z, f1.w);
      d1.x = pack2(f2.x, f2.y); d1.y = pack2(f2.z, f2.w);
      d1.z = pack2(f3.x, f3.y); d1.w = pack2(f3.z, f3.w);
      uint4* dp = (uint4*)(xl + tid * XSTRA);
      dp[0] = d0; dp[1] = d1;
    }
    __syncthreads();
    bf16x8 af = {0, 0, 0, 0, 0, 0, 0, 0};
    if (quad < 2) af = *(const bf16x8*)(xl + l15 * XSTRA + quad * 8);
    float a0r = 0.f, a1r = 0.f, a2r = 0.f, a3r = 0.f;
    float b0r = 0.f, b1r = 0.f, b2r = 0.f, b3r = 0.f;
    #pragma unroll
    for (int t = 0; t < 16; ++t) {
      const int tile = wave * 16 + t;
      bf16x8 bfr = {0, 0, 0, 0, 0, 0, 0, 0};
      if (quad < 2)
        bfr = *(const bf16x8*)(wl + ((size_t)tile * 16 + l15) * WSTR + quad * 8);
      f32x4 p = {0.f, 0.f, 0.f, 0.f};
      p = __builtin_amdgcn_mfma_f32_16x16x32_bf16(af, bfr, p, 0, 0, 0);
      const int jo = tile * 16 + l15;
      const size_t vb = (size_t)(b0 + quad * 4) * JO_ + jo;
      a0r += p[0] * v0[vb];
      a1r += p[1] * v0[vb + JO_];
      a2r += p[2] * v0[vb + 2 * JO_];
      a3r += p[3] * v0[vb + 3 * JO_];
      if (iter == 2) {
        b0r += p[0] * v1[vb];
        b1r += p[1] * v1[vb + JO_];
        b2r += p[2] * v1[vb + 2 * JO_];
        b3r += p[3] * v1[vb + 3 * JO_];
      }
      if (t & 1) {
        float s0 = a0r + b0r, s1 = a1r + b1r, s2 = a2r + b2r, s3 = a3r + b3r;
        #pragma unroll
        for (int m = 1; m <= 8; m <<= 1) {
          s0 += __shfl_xor(s0, m, 64);
          s1 += __shfl_xor(s1, m, 64);
          s2 += __shfl_xor(s2, m, 64);
          s3 += __shfl_xor(s3, m, 64);
        }
        if (l15 == 0) {
          const int jj = tile >> 1;
          ag[quad * 4 + 0][jj] = s0;
          ag[quad * 4 + 1][jj] = s1;
          ag[quad * 4 + 2][jj] = s2;
          ag[quad * 4 + 3][jj] = s3;
        }
        a0r = a1r = a2r = a3r = 0.f;
        b0r = b1r = b2r = b3r = 0.f;
      }
    }
    __syncthreads();
    if (tid < 16) {
      const int b = b0 + tid;
      const size_t rowoff = ((size_t)b * N_ + n) * J_;
      float mx = -1e30f;
      #pragma unroll
      for (int jj = 0; jj < J_; ++jj) mx = fmaxf(mx, ag[tid][jj]);
      float sum = 0.f;
      float e[J_];
      #pragma unroll
      for (int jj = 0; jj < J_; ++jj) {
        e[jj] = __expf(ag[tid][jj] - mx);
        sum += e[jj];
      }
      const float inv = 1.f / sum;
      #pragma unroll
      for (int jj = 0; jj < J_; ++jj)
        cb[rowoff + jj] = f2bf(e[jj] * inv);
    }
  }
}

// ---------------------------------------------------------------------------
extern "C" void kernel_launch(void* const* d_in, const int* in_sizes, int n_in,
                              void* d_out, int out_size, void* d_ws, size_t ws_size,
                              hipStream_t stream) {
  const float* x = (const float*)d_in[0];
  const float* w = (const float*)d_in[1];
  float* out = (float*)d_out;
  char* ws = (char*)d_ws;
  // footprint: 8 MB + 3*256 KB = 8.75 MB
  u16*   c_bf  = (u16*)ws;                                   // 8 MB
  float* s_sum = (float*)(ws + (size_t)8 * 1024 * 1024);     // 256 KB
  float* v0    = (float*)(ws + (size_t)8 * 1024 * 1024 + 262144);
  float* v1    = (float*)(ws + (size_t)8 * 1024 * 1024 + 2 * 262144);

  dim3 sg(64, 32), sb(256);
  dim3 rg(1024), rb(64);
  dim3 agd(256, 4), ab(256);
  const size_t s_bytes = (size_t)B_ * JO_ * sizeof(float);

  // iter 0: uniform c = 1/32
  hipMemsetAsync(s_sum, 0, s_bytes, stream);
  s_kernel<<<sg, sb, 0, stream>>>(x, w, c_bf, s_sum, 1);
  r_kernel<<<rg, rb, 0, stream>>>(s_sum, v0, out, 0);
  // iter 1
  a_kernel<<<agd, ab, 0, stream>>>(x, w, v0, v1, c_bf, 1);
  hipMemsetAsync(s_sum, 0, s_bytes, stream);
  s_kernel<<<sg, sb, 0, stream>>>(x, w, c_bf, s_sum, 0);
  r_kernel<<<rg, rb, 0, stream>>>(s_sum, v1, out, 0);
  // iter 2
  a_kernel<<<agd, ab, 0, stream>>>(x, w, v0, v1, c_bf, 2);
  hipMemsetAsync(s_sum, 0, s_bytes, stream);
  s_kernel<<<sg, sb, 0, stream>>>(x, w, c_bf, s_sum, 0);
  r_kernel<<<rg, rb, 0, stream>>>(s_sum, v0, out, 1);
}

// Round 4
// 534.773 us; speedup vs baseline: 1.1341x; 1.1341x over previous
//
#include <hip/hip_runtime.h>
#include <hip/hip_bf16.h>

#define B_ 64
#define N_ 2048
#define I_ 16
#define J_ 32
#define O_ 32
#define JO_ 1024

typedef __attribute__((ext_vector_type(8))) short bf16x8;
typedef __attribute__((ext_vector_type(4))) float f32x4;
typedef unsigned short u16;
typedef unsigned int u32;

__device__ __forceinline__ float bf2f(u16 u) {
  union { u32 i; float f; } c; c.i = ((u32)u) << 16; return c.f;
}
__device__ __forceinline__ u16 f2bf(float f) {
  union { float f; u32 i; } c; c.f = f;
  u32 r = (c.i + 0x7fffu + ((c.i >> 16) & 1u)) >> 16;
  return (u16)r;
}
__device__ __forceinline__ u32 pack2(float a, float b) {
  return (u32)f2bf(a) | ((u32)f2bf(b) << 16);
}
__device__ __forceinline__ u32 scale2(u32 p, float cv) {
  return pack2(bf2f((u16)(p & 0xffffu)) * cv, bf2f((u16)(p >> 16)) * cv);
}

// ---------------------------------------------------------------------------
// xconv: x f32 -> xb bf16 (2M elements, 8 per thread)
// ---------------------------------------------------------------------------
__global__ __launch_bounds__(256) void xconv_kernel(
    const float* __restrict__ xf, u16* __restrict__ xb)
{
  const int idx = (blockIdx.x * 256 + threadIdx.x) * 8;
  const float4 a = *(const float4*)(xf + idx);
  const float4 b = *(const float4*)(xf + idx + 4);
  uint4 d;
  d.x = pack2(a.x, a.y); d.y = pack2(a.z, a.w);
  d.z = pack2(b.x, b.y); d.w = pack2(b.z, b.w);
  *(uint4*)(xb + idx) = d;
}

// ---------------------------------------------------------------------------
// S kernel: s[b][j][o] += sum_{n,i} (c[b,n,j]*x[b,n,i]) * w[n,j,o,i]
// grid (64 ksplit, 32 j), block 256, fp32 atomic accumulate into 256KB s_sum.
// first=1: read w from f32 and write wb (bf16) as side effect (runs once).
// ---------------------------------------------------------------------------
#define S_NPB 32
#define S_CHUNK 8
#define XSTR 136   // 128 + 8 pad, 272B rows (16B aligned)

__global__ __launch_bounds__(256, 2) void s_kernel(
    const u16* __restrict__ xb, const float* __restrict__ wf,
    u16* __restrict__ wb_g, const u16* __restrict__ cb,
    float* __restrict__ s_sum, int uniform, int first)
{
  __shared__ u16 xs[B_ * XSTR];   // 17 KB
  __shared__ u16 wl[O_ * XSTR];   // 8.5 KB
  const int tid = threadIdx.x;
  const int lane = tid & 63, wave = tid >> 6;
  const int l15 = lane & 15, quad = lane >> 4;
  const int j = blockIdx.y;
  const int n0 = blockIdx.x * S_NPB;
  f32x4 acc0 = {0.f, 0.f, 0.f, 0.f}, acc1 = {0.f, 0.f, 0.f, 0.f};

  for (int ch = 0; ch < S_NPB / S_CHUNK; ++ch) {
    const int nc = n0 + ch * S_CHUNK;
    __syncthreads();
    // stage c-scaled x (bf16 source): 512 rows (b, ln) of 16 bf16
    for (int r = tid; r < B_ * S_CHUNK; r += 256) {
      const int b = r >> 3, ln = r & 7, n = nc + ln;
      const float cv = uniform ? 0.03125f
                               : bf2f(cb[((size_t)b * N_ + n) * J_ + j]);
      const uint4* sp = (const uint4*)(xb + ((size_t)b * N_ + n) * I_);
      uint4 lo = sp[0], hi = sp[1];
      uint4 d0, d1;
      d0.x = scale2(lo.x, cv); d0.y = scale2(lo.y, cv);
      d0.z = scale2(lo.z, cv); d0.w = scale2(lo.w, cv);
      d1.x = scale2(hi.x, cv); d1.y = scale2(hi.y, cv);
      d1.z = scale2(hi.z, cv); d1.w = scale2(hi.w, cv);
      uint4* dp = (uint4*)(xs + b * XSTR + ln * I_);
      dp[0] = d0; dp[1] = d1;
    }
    // stage w: 256 rows (ln, o) of 16 bf16 — one per thread
    {
      const int ln = tid >> 5, o = tid & 31, n = nc + ln;
      const size_t jo_row = (size_t)n * JO_ + (size_t)j * O_ + o;
      uint4 d0, d1;
      if (first) {
        const float4* sp = (const float4*)(wf + jo_row * I_);
        float4 f0 = sp[0], f1 = sp[1], f2 = sp[2], f3 = sp[3];
        d0.x = pack2(f0.x, f0.y); d0.y = pack2(f0.z, f0.w);
        d0.z = pack2(f1.x, f1.y); d0.w = pack2(f1.z, f1.w);
        d1.x = pack2(f2.x, f2.y); d1.y = pack2(f2.z, f2.w);
        d1.z = pack2(f3.x, f3.y); d1.w = pack2(f3.z, f3.w);
        uint4* wp = (uint4*)(wb_g + jo_row * I_);
        wp[0] = d0; wp[1] = d1;               // each w row written exactly once
      } else {
        const uint4* sp = (const uint4*)(wb_g + jo_row * I_);
        d0 = sp[0]; d1 = sp[1];
      }
      uint4* dp = (uint4*)(wl + o * XSTR + ln * I_);
      dp[0] = d0; dp[1] = d1;
    }
    __syncthreads();
    #pragma unroll
    for (int ks = 0; ks < 4; ++ks) {
      const int kk = ks * 32 + quad * 8;
      bf16x8 av = *(const bf16x8*)(xs + (wave * 16 + l15) * XSTR + kk);
      bf16x8 b0 = *(const bf16x8*)(wl + l15 * XSTR + kk);
      bf16x8 b1 = *(const bf16x8*)(wl + (16 + l15) * XSTR + kk);
      acc0 = __builtin_amdgcn_mfma_f32_16x16x32_bf16(av, b0, acc0, 0, 0, 0);
      acc1 = __builtin_amdgcn_mfma_f32_16x16x32_bf16(av, b1, acc1, 0, 0, 0);
    }
  }
  // C layout: col = lane&15, row = quad*4 + reg
  #pragma unroll
  for (int r = 0; r < 4; ++r) {
    const int b = wave * 16 + quad * 4 + r;
    atomicAdd(&s_sum[(size_t)b * JO_ + (size_t)j * O_ + l15], acc0[r]);
    atomicAdd(&s_sum[(size_t)b * JO_ + (size_t)j * O_ + 16 + l15], acc1[r]);
  }
}

// ---------------------------------------------------------------------------
// R kernel: squash over o, write v fp32 (and fp32 out on final)
// ---------------------------------------------------------------------------
__global__ __launch_bounds__(64) void r_kernel(
    const float* __restrict__ s_sum, float* __restrict__ v,
    float* __restrict__ out, int final_)
{
  const int o = threadIdx.x & 31;
  const int pair = blockIdx.x * 2 + (threadIdx.x >> 5);   // pair = b*32 + j
  const size_t off = (size_t)pair * O_ + o;
  float s = s_sum[off];
  float sq = s * s;
  #pragma unroll
  for (int m = 16; m >= 1; m >>= 1) sq += __shfl_xor(sq, m, 64);
  const float scale = sq / (1.f + sq) * rsqrtf(sq + 1e-8f);
  const float vv = scale * s;
  v[off] = vv;
  if (final_) out[off] = vv;
}

// ---------------------------------------------------------------------------
// A kernel: per wave-n: pred = x*w via MFMA (bf16 w direct from global),
// agreement = sum_o pred * vsum (vsum = va + alpha*vb, staged once in LDS,
// transposed [jo][b]), softmax over j -> c (bf16). No barriers in n-loop.
// grid 512 (= 128 n-groups x 4 b-quarters), block 256 (4 waves, A_GN n each).
// ---------------------------------------------------------------------------
#define A_GN 4
#define VQS 20   // u16 stride per jo row (16 b + 4 pad = 40 B, 8B-aligned)

__global__ __launch_bounds__(256, 2) void a_kernel(
    const u16* __restrict__ xb, const u16* __restrict__ wb,
    const float* __restrict__ va, const float* __restrict__ vb,
    u16* __restrict__ cb, float alpha)
{
  __shared__ u16 vq[JO_ * VQS];      // 40 KB, [jo][b_local]
  __shared__ float ag[4][16][36];    // 9 KB, [wave][b_local][j]
  const int tid = threadIdx.x;
  const int lane = tid & 63, wave = tid >> 6;
  const int l15 = lane & 15, quad = lane >> 4;
  const int group = blockIdx.x >> 2, quarter = blockIdx.x & 3;
  const int b0 = quarter * 16;
  const int ng0 = group * (4 * A_GN);

  // stage vsum -> bf16 LDS transposed (once per block)
  for (int idx = tid; idx < 16 * JO_; idx += 256) {
    const int r = idx >> 10, jo = idx & 1023;
    const size_t g = (size_t)(b0 + r) * JO_ + jo;
    vq[jo * VQS + r] = f2bf(va[g] + alpha * vb[g]);
  }
  __syncthreads();

  #pragma unroll 1
  for (int nl = 0; nl < A_GN; ++nl) {
    const int n = ng0 + wave * A_GN + nl;
    // A-frag: A[m=l15][k=quad*8+idx], k>=16 zero (quads 2,3)
    bf16x8 af = {0, 0, 0, 0, 0, 0, 0, 0};
    if (quad < 2)
      af = *(const bf16x8*)(xb + ((size_t)(b0 + l15) * N_ + n) * I_ + quad * 8);
    float s0 = 0.f, s1 = 0.f, s2 = 0.f, s3 = 0.f;
    #pragma unroll
    for (int t = 0; t < 64; ++t) {
      bf16x8 bfr = {0, 0, 0, 0, 0, 0, 0, 0};
      if (quad < 2)   // quads 2,3: A is zero there, B value irrelevant
        bfr = *(const bf16x8*)(wb + ((size_t)n * JO_ + t * 16 + l15) * I_ + quad * 8);
      f32x4 p = {0.f, 0.f, 0.f, 0.f};
      p = __builtin_amdgcn_mfma_f32_16x16x32_bf16(af, bfr, p, 0, 0, 0);
      // p[r] = pred[b0+quad*4+r][jo=t*16+l15]
      const ushort4 vv = *(const ushort4*)(vq + (t * 16 + l15) * VQS + quad * 4);
      s0 += p[0] * bf2f(vv.x);
      s1 += p[1] * bf2f(vv.y);
      s2 += p[2] * bf2f(vv.z);
      s3 += p[3] * bf2f(vv.w);
      if (t & 1) {   // j = t>>1 complete: butterfly over 16 o-lanes
        #pragma unroll
        for (int m = 1; m <= 8; m <<= 1) {
          s0 += __shfl_xor(s0, m, 64);
          s1 += __shfl_xor(s1, m, 64);
          s2 += __shfl_xor(s2, m, 64);
          s3 += __shfl_xor(s3, m, 64);
        }
        if (l15 == 0) {
          const int j = t >> 1;
          ag[wave][quad * 4 + 0][j] = s0;
          ag[wave][quad * 4 + 1][j] = s1;
          ag[wave][quad * 4 + 2][j] = s2;
          ag[wave][quad * 4 + 3][j] = s3;
        }
        s0 = s1 = s2 = s3 = 0.f;
      }
    }
    __threadfence_block();   // ds_write -> ds_read within wave
    // softmax: lane (quad,l15): row=l15, j = quad*8 + jj
    const float* agp = &ag[wave][l15][quad * 8];
    float e0 = agp[0], e1 = agp[1], e2 = agp[2], e3 = agp[3];
    float e4 = agp[4], e5 = agp[5], e6 = agp[6], e7 = agp[7];
    float mx = fmaxf(fmaxf(fmaxf(e0, e1), fmaxf(e2, e3)),
                     fmaxf(fmaxf(e4, e5), fmaxf(e6, e7)));
    mx = fmaxf(mx, __shfl_xor(mx, 16, 64));
    mx = fmaxf(mx, __shfl_xor(mx, 32, 64));
    e0 = __expf(e0 - mx); e1 = __expf(e1 - mx);
    e2 = __expf(e2 - mx); e3 = __expf(e3 - mx);
    e4 = __expf(e4 - mx); e5 = __expf(e5 - mx);
    e6 = __expf(e6 - mx); e7 = __expf(e7 - mx);
    float sum = ((e0 + e1) + (e2 + e3)) + ((e4 + e5) + (e6 + e7));
    sum += __shfl_xor(sum, 16, 64);
    sum += __shfl_xor(sum, 32, 64);
    const float inv = 1.f / sum;
    uint4 st;
    st.x = pack2(e0 * inv, e1 * inv); st.y = pack2(e2 * inv, e3 * inv);
    st.z = pack2(e4 * inv, e5 * inv); st.w = pack2(e6 * inv, e7 * inv);
    *(uint4*)(cb + ((size_t)(b0 + l15) * N_ + n) * J_ + quad * 8) = st;
  }
}

// ---------------------------------------------------------------------------
extern "C" void kernel_launch(void* const* d_in, const int* in_sizes, int n_in,
                              void* d_out, int out_size, void* d_ws, size_t ws_size,
                              hipStream_t stream) {
  const float* x = (const float*)d_in[0];
  const float* w = (const float*)d_in[1];
  float* out = (float*)d_out;
  char* ws = (char*)d_ws;
  // layout: wb 64MB | cb 8MB | xb 4MB | s_sum 256K | v0 | v1   (~76.75 MB)
  u16*   wb    = (u16*)ws;
  u16*   cb    = (u16*)(ws + (size_t)64 * 1024 * 1024);
  u16*   xb    = (u16*)(ws + (size_t)72 * 1024 * 1024);
  float* s_sum = (float*)(ws + (size_t)76 * 1024 * 1024);
  float* v0    = (float*)(ws + (size_t)76 * 1024 * 1024 + 262144);
  float* v1    = (float*)(ws + (size_t)76 * 1024 * 1024 + 2 * 262144);

  dim3 sg(64, 32), sb(256);
  dim3 rg(1024), rb(64);
  dim3 agd(512), ab(256);
  const size_t s_bytes = (size_t)B_ * JO_ * sizeof(float);

  xconv_kernel<<<dim3(1024), dim3(256), 0, stream>>>(x, xb);
  // iter 0: uniform c = 1/32; converts w -> wb on the fly
  hipMemsetAsync(s_sum, 0, s_bytes, stream);
  s_kernel<<<sg, sb, 0, stream>>>(xb, w, wb, cb, s_sum, 1, 1);
  r_kernel<<<rg, rb, 0, stream>>>(s_sum, v0, out, 0);
  // iter 1: logits = ag(v0)
  a_kernel<<<agd, ab, 0, stream>>>(xb, wb, v0, v0, cb, 0.0f);
  hipMemsetAsync(s_sum, 0, s_bytes, stream);
  s_kernel<<<sg, sb, 0, stream>>>(xb, w, wb, cb, s_sum, 0, 0);
  r_kernel<<<rg, rb, 0, stream>>>(s_sum, v1, out, 0);
  // iter 2: logits = ag(v0) + ag(v1) = sum_o pred*(v0+v1)
  a_kernel<<<agd, ab, 0, stream>>>(xb, wb, v0, v1, cb, 1.0f);
  hipMemsetAsync(s_sum, 0, s_bytes, stream);
  s_kernel<<<sg, sb, 0, stream>>>(xb, w, wb, cb, s_sum, 0, 0);
  r_kernel<<<rg, rb, 0, stream>>>(s_sum, v0, out, 1);
}